// Round 1
// baseline (2362.764 us; speedup 1.0000x reference)
//
#include <hip/hip_runtime.h>
#include <hip/hip_bf16.h>

typedef short bf16x8 __attribute__((ext_vector_type(8)));
typedef float f32x4 __attribute__((ext_vector_type(4)));

#define GLDS16(gp, lp)                                                         \
  __builtin_amdgcn_global_load_lds(                                            \
      (const __attribute__((address_space(1))) void*)(gp),                     \
      (__attribute__((address_space(3))) void*)(lp), 16, 0, 0)

static __device__ __forceinline__ unsigned short f2bf(float f) {
  unsigned u = __float_as_uint(f);
  u += 0x7fffu + ((u >> 16) & 1u);  // RNE; inputs are finite
  return (unsigned short)(u >> 16);
}

// ---------------------------------------------------------------------------
// Weight transpose + fp32->bf16 convert: w[K][N] f32 -> wt[N][K] bf16
// grid (N/32, K/32), block 256
// ---------------------------------------------------------------------------
__global__ __launch_bounds__(256) void wt_transpose_kernel(
    const float* __restrict__ w, unsigned short* __restrict__ wt, int K, int N) {
  __shared__ float tile[32][33];
  const int n0 = blockIdx.x * 32, k0 = blockIdx.y * 32;
  const int tx = threadIdx.x & 31, ty = threadIdx.x >> 5;  // ty: 0..7
#pragma unroll
  for (int i = 0; i < 4; ++i) {
    const int k = ty + i * 8;
    tile[k][tx] = w[(size_t)(k0 + k) * N + n0 + tx];
  }
  __syncthreads();
#pragma unroll
  for (int i = 0; i < 4; ++i) {
    const int n = ty + i * 8;
    wt[(size_t)(n0 + n) * K + k0 + tx] = f2bf(tile[tx][n]);
  }
}

// ---------------------------------------------------------------------------
// LayerNorm over C=512, fp32 in -> bf16 out. 1 wave per token, 4 tokens/block.
// ---------------------------------------------------------------------------
__global__ __launch_bounds__(256) void ln_bf16_kernel(
    const float* __restrict__ x, const float* __restrict__ gw,
    const float* __restrict__ bw, unsigned short* __restrict__ out) {
  const int wv = threadIdx.x >> 6, lane = threadIdx.x & 63;
  const size_t t = (size_t)blockIdx.x * 4 + wv;
  const float4* xr = (const float4*)(x + t * 512);
  const float4 v0 = xr[lane * 2];
  const float4 v1 = xr[lane * 2 + 1];
  float s = v0.x + v0.y + v0.z + v0.w + v1.x + v1.y + v1.z + v1.w;
  float ss = v0.x * v0.x + v0.y * v0.y + v0.z * v0.z + v0.w * v0.w +
             v1.x * v1.x + v1.y * v1.y + v1.z * v1.z + v1.w * v1.w;
#pragma unroll
  for (int m = 1; m < 64; m <<= 1) {
    s += __shfl_xor(s, m);
    ss += __shfl_xor(ss, m);
  }
  const float mean = s * (1.0f / 512.0f);
  const float var = fmaxf(ss * (1.0f / 512.0f) - mean * mean, 0.0f);
  const float rstd = rsqrtf(var + 1e-3f);
  const float4* gp = (const float4*)gw;
  const float4* bp = (const float4*)bw;
  const float4 g0 = gp[lane * 2], g1 = gp[lane * 2 + 1];
  const float4 b0 = bp[lane * 2], b1 = bp[lane * 2 + 1];
  uint4 o;
  o.x = (unsigned)f2bf((v0.x - mean) * rstd * g0.x + b0.x) |
        ((unsigned)f2bf((v0.y - mean) * rstd * g0.y + b0.y) << 16);
  o.y = (unsigned)f2bf((v0.z - mean) * rstd * g0.z + b0.z) |
        ((unsigned)f2bf((v0.w - mean) * rstd * g0.w + b0.w) << 16);
  o.z = (unsigned)f2bf((v1.x - mean) * rstd * g1.x + b1.x) |
        ((unsigned)f2bf((v1.y - mean) * rstd * g1.y + b1.y) << 16);
  o.w = (unsigned)f2bf((v1.z - mean) * rstd * g1.z + b1.z) |
        ((unsigned)f2bf((v1.w - mean) * rstd * g1.w + b1.w) << 16);
  *(uint4*)(out + t * 512 + lane * 8) = o;
}

// ---------------------------------------------------------------------------
// m97-style bf16 GEMM: C[M][N] = A[M][K] @ Bt[N][K]^T + bias (+resid) (+gelu)
// 128x128 tile, BK=64, 4 waves (2x2), 16x16x32 MFMA, global_load_lds staging.
// EPI: 0 = bf16 out, 1 = f32 out (+resid), 2 = bf16 gelu(out)
// M%128==0, N%128==0, K%64==0, grid = (M/128)*(N/128) (divisible by 8).
// ---------------------------------------------------------------------------
template <int EPI>
__global__ __launch_bounds__(256) void gemm_bf16_kernel(
    const unsigned short* __restrict__ A, const unsigned short* __restrict__ Bt,
    const float* __restrict__ bias, const float* __restrict__ resid,
    void* __restrict__ outv, int M, int N, int K) {
  __shared__ __align__(16) unsigned short sA[128 * 64];
  __shared__ __align__(16) unsigned short sB[128 * 64];
  const int nTn = N >> 7;
  const int nwg = gridDim.x;
  const int bid = blockIdx.x;
  const int swz = (bid & 7) * (nwg >> 3) + (bid >> 3);  // XCD-aware swizzle
  const int tm = swz / nTn, tn = swz % nTn;
  const int lane = threadIdx.x & 63, wv = threadIdx.x >> 6;
  const int wm = wv >> 1, wn = wv & 1;
  const int lr = lane & 15, lg = lane >> 4;
  const unsigned short* Ab =
      A + (size_t)tm * 128 * K + (size_t)(lane >> 3) * K + (lane & 7) * 8;
  const unsigned short* Bb =
      Bt + (size_t)tn * 128 * K + (size_t)(lane >> 3) * K + (lane & 7) * 8;
  f32x4 acc[4][4] = {};
  for (int kt = 0; kt < K; kt += 64) {
#pragma unroll
    for (int i = 0; i < 4; ++i) {
      const int r0 = (wv * 4 + i) * 8;  // 8 rows per wave-load
      GLDS16(Ab + (size_t)r0 * K + kt, &sA[r0 * 64]);
      GLDS16(Bb + (size_t)r0 * K + kt, &sB[r0 * 64]);
    }
    __syncthreads();
#pragma unroll
    for (int kk = 0; kk < 2; ++kk) {
      bf16x8 af[4], bf[4];
#pragma unroll
      for (int m = 0; m < 4; ++m)
        af[m] = *(const bf16x8*)&sA[(wm * 64 + m * 16 + lr) * 64 + kk * 32 + lg * 8];
#pragma unroll
      for (int n = 0; n < 4; ++n)
        bf[n] = *(const bf16x8*)&sB[(wn * 64 + n * 16 + lr) * 64 + kk * 32 + lg * 8];
#pragma unroll
      for (int m = 0; m < 4; ++m)
#pragma unroll
        for (int n = 0; n < 4; ++n)
          acc[m][n] = __builtin_amdgcn_mfma_f32_16x16x32_bf16(af[m], bf[n],
                                                              acc[m][n], 0, 0, 0);
    }
    __syncthreads();
  }
  const int row0 = tm * 128 + wm * 64 + lg * 4;
  const int col0 = tn * 128 + wn * 64 + lr;
#pragma unroll
  for (int n = 0; n < 4; ++n) {
    const int col = col0 + n * 16;
    const float bs = bias[col];
#pragma unroll
    for (int m = 0; m < 4; ++m) {
#pragma unroll
      for (int r = 0; r < 4; ++r) {
        const size_t idx = (size_t)(row0 + m * 16 + r) * N + col;
        float v = acc[m][n][r] + bs;
        if (EPI == 1) {
          ((float*)outv)[idx] = v + resid[idx];
        } else if (EPI == 2) {
          v = 0.5f * v * (1.0f + erff(v * 0.70710678118f));
          ((unsigned short*)outv)[idx] = f2bf(v);
        } else {
          ((unsigned short*)outv)[idx] = f2bf(v);
        }
      }
    }
  }
}

// ---------------------------------------------------------------------------
// Window attention: 1 wave per (window, head). WS=16, D=64, H=8.
// qkv: [ntok][3*512] bf16, layout per token: [3][H][64].
// scores = (Q*0.125) K^T + bias ; softmax over k ; O^T = V^T P^T via MFMA.
// out: [ntok][512] bf16 (token-major, h*64+d).
// ---------------------------------------------------------------------------
__global__ __launch_bounds__(256) void attn_kernel(
    const unsigned short* __restrict__ qkv,
    const float* __restrict__ bias_table, unsigned short* __restrict__ out) {
  __shared__ __align__(16) unsigned short sVt[4][64 * 16];  // [d][kk] per wave
  __shared__ __align__(16) unsigned short sP[4][16 * 16];   // [q][kk] per wave
  const int wv = threadIdx.x >> 6, lane = threadIdx.x & 63;
  const int task = blockIdx.x * 4 + wv;  // 65536 tasks
  const int w = task >> 3, h = task & 7;
  const int c = lane & 15, g = lane >> 4;
  const unsigned short* base =
      qkv + (size_t)w * 16 * 1536 + (size_t)c * 1536 + h * 64;
  // Q,K fragments: lane holds token c, dims g*8..g*8+7 (and +32)
  const bf16x8 qf0 = *(const bf16x8*)(base + g * 8);
  const bf16x8 qf1 = *(const bf16x8*)(base + 32 + g * 8);
  const bf16x8 kf0 = *(const bf16x8*)(base + 512 + g * 8);
  const bf16x8 kf1 = *(const bf16x8*)(base + 512 + 32 + g * 8);
  const bf16x8 vf0 = *(const bf16x8*)(base + 1024 + g * 8);
  const bf16x8 vf1 = *(const bf16x8*)(base + 1024 + 32 + g * 8);
  unsigned short* vt = sVt[wv];
#pragma unroll
  for (int j = 0; j < 8; ++j) vt[(g * 8 + j) * 16 + c] = (unsigned short)vf0[j];
#pragma unroll
  for (int j = 0; j < 8; ++j) vt[(32 + g * 8 + j) * 16 + c] = (unsigned short)vf1[j];
  // scores: lane holds s[q=g*4+r][kk=c]
  f32x4 s = {0.f, 0.f, 0.f, 0.f};
  s = __builtin_amdgcn_mfma_f32_16x16x32_bf16(qf0, kf0, s, 0, 0, 0);
  s = __builtin_amdgcn_mfma_f32_16x16x32_bf16(qf1, kf1, s, 0, 0, 0);
  float p[4];
#pragma unroll
  for (int r = 0; r < 4; ++r) {
    const int q = g * 4 + r;
    p[r] = s[r] * 0.125f + bias_table[(q - c + 15) * 8 + h];
  }
#pragma unroll
  for (int r = 0; r < 4; ++r) {  // softmax over the 16 kk lanes of this group
    float m = p[r];
    m = fmaxf(m, __shfl_xor(m, 1));
    m = fmaxf(m, __shfl_xor(m, 2));
    m = fmaxf(m, __shfl_xor(m, 4));
    m = fmaxf(m, __shfl_xor(m, 8));
    const float e = __expf(p[r] - m);
    float t = e;
    t += __shfl_xor(t, 1);
    t += __shfl_xor(t, 2);
    t += __shfl_xor(t, 4);
    t += __shfl_xor(t, 8);
    p[r] = e * __builtin_amdgcn_rcpf(t);
  }
  unsigned short* pb = sP[wv];
#pragma unroll
  for (int r = 0; r < 4; ++r) pb[(g * 4 + r) * 16 + c] = f2bf(p[r]);
  __syncthreads();
  // PV: O^T[d][q] = sum_kk V^T[d][kk] * P^T[kk][q], K padded to 32 (P=0 top).
  bf16x8 pf;
#pragma unroll
  for (int j = 0; j < 8; ++j) pf[j] = 0;
  if (g < 2) pf = *(const bf16x8*)&pb[c * 16 + g * 8];
  const int kk0 = (g & 1) * 8;  // clamp reads for g>=2 (multiplied by P=0)
  unsigned short* ob = out + (size_t)w * 16 * 512 + (size_t)c * 512 + h * 64;
#pragma unroll
  for (int ch = 0; ch < 4; ++ch) {
    const bf16x8 av = *(const bf16x8*)&vt[(ch * 16 + c) * 16 + kk0];
    f32x4 o = {0.f, 0.f, 0.f, 0.f};
    o = __builtin_amdgcn_mfma_f32_16x16x32_bf16(av, pf, o, 0, 0, 0);
    // lane holds O[q=c][d = ch*16 + g*4 + r], r consecutive -> pack 4 bf16
    ushort4 pk;
    pk.x = f2bf(o[0]);
    pk.y = f2bf(o[1]);
    pk.z = f2bf(o[2]);
    pk.w = f2bf(o[3]);
    *(ushort4*)(ob + ch * 16 + g * 4) = pk;
  }
}

// ---------------------------------------------------------------------------
extern "C" void kernel_launch(void* const* d_in, const int* in_sizes, int n_in,
                              void* d_out, int out_size, void* d_ws,
                              size_t ws_size, hipStream_t stream) {
  (void)in_sizes; (void)n_in; (void)out_size;
  const float* x      = (const float*)d_in[0];
  const float* g1     = (const float*)d_in[1];
  const float* b1     = (const float*)d_in[2];
  const float* w_qkv  = (const float*)d_in[3];
  const float* b_qkv  = (const float*)d_in[4];
  const float* btab   = (const float*)d_in[5];
  const float* w_proj = (const float*)d_in[6];
  const float* b_proj = (const float*)d_in[7];
  const float* g2     = (const float*)d_in[8];
  const float* b2     = (const float*)d_in[9];
  const float* w_fc1  = (const float*)d_in[10];
  const float* b_fc1  = (const float*)d_in[11];
  const float* w_fc2  = (const float*)d_in[12];
  const float* b_fc2  = (const float*)d_in[13];
  float* out = (float*)d_out;

  // Workspace layout (bytes):
  //   [0, 128M)           h / h2 bf16            (131072*512*2)
  //   [128M, 128M+512M)   qkv bf16 (384M) with attn_out bf16 (128M) at its
  //                       tail; whole 512M reused as mlp hidden bf16
  //   [640M, 640M+6M)     transposed bf16 weights
  char* ws = (char*)d_ws;
  const size_t OFF_BIG = 134217728ull;           // 128M
  const size_t OFF_ATT = OFF_BIG + 402653184ull; // 128M + 384M
  const size_t OFF_WT  = OFF_BIG + 536870912ull; // 128M + 512M
  if (ws_size < OFF_WT + 6291456ull) return;     // need ~646 MB
  unsigned short* hbuf   = (unsigned short*)(ws);
  unsigned short* qkvhid = (unsigned short*)(ws + OFF_BIG);
  unsigned short* attnb  = (unsigned short*)(ws + OFF_ATT);
  unsigned short* wqkvT  = (unsigned short*)(ws + OFF_WT);
  unsigned short* wprojT = wqkvT + 512 * 1536;
  unsigned short* wfc1T  = wprojT + 512 * 512;
  unsigned short* wfc2T  = wfc1T + 512 * 2048;

  // weights: [K][N] f32 -> [N][K] bf16
  wt_transpose_kernel<<<dim3(1536 / 32, 512 / 32), 256, 0, stream>>>(w_qkv, wqkvT, 512, 1536);
  wt_transpose_kernel<<<dim3(512 / 32, 512 / 32), 256, 0, stream>>>(w_proj, wprojT, 512, 512);
  wt_transpose_kernel<<<dim3(2048 / 32, 512 / 32), 256, 0, stream>>>(w_fc1, wfc1T, 512, 2048);
  wt_transpose_kernel<<<dim3(512 / 32, 2048 / 32), 256, 0, stream>>>(w_fc2, wfc2T, 2048, 512);

  // 1) h = LN1(x)  (bf16)
  ln_bf16_kernel<<<32768, 256, 0, stream>>>(x, g1, b1, hbuf);
  // 2) qkv = h @ w_qkv + b_qkv  (bf16)
  gemm_bf16_kernel<0><<<12288, 256, 0, stream>>>(hbuf, wqkvT, b_qkv, nullptr,
                                                 qkvhid, 131072, 1536, 512);
  // 3) window attention -> attn_out (bf16)
  attn_kernel<<<16384, 256, 0, stream>>>(qkvhid, btab, attnb);
  // 4) x1 = attn_out @ w_proj + b_proj + x  (f32, into d_out)
  gemm_bf16_kernel<1><<<4096, 256, 0, stream>>>(attnb, wprojT, b_proj, x, out,
                                                131072, 512, 512);
  // 5) h2 = LN2(x1)  (bf16)
  ln_bf16_kernel<<<32768, 256, 0, stream>>>(out, g2, b2, hbuf);
  // 6) hid = gelu(h2 @ w_fc1 + b_fc1)  (bf16)
  gemm_bf16_kernel<2><<<16384, 256, 0, stream>>>(hbuf, wfc1T, b_fc1, nullptr,
                                                 qkvhid, 131072, 2048, 512);
  // 7) out = hid @ w_fc2 + b_fc2 + x1  (f32, in-place on d_out)
  gemm_bf16_kernel<1><<<4096, 256, 0, stream>>>(qkvhid, wfc2T, b_fc2, out, out,
                                                131072, 512, 2048);
}

// Round 3
// 1980.616 us; speedup vs baseline: 1.1929x; 1.1929x over previous
//
#include <hip/hip_runtime.h>
#include <hip/hip_bf16.h>

typedef short bf16x8 __attribute__((ext_vector_type(8)));
typedef float f32x4 __attribute__((ext_vector_type(4)));

#define GLDS16(gp, lp)                                                         \
  __builtin_amdgcn_global_load_lds(                                            \
      (const __attribute__((address_space(1))) void*)(gp),                     \
      (__attribute__((address_space(3))) void*)(lp), 16, 0, 0)
#define BAR() __builtin_amdgcn_s_barrier()
#define SCHED0() __builtin_amdgcn_sched_barrier(0)
#define PRIO(p) __builtin_amdgcn_s_setprio(p)
#define MFMA(a, b, c) __builtin_amdgcn_mfma_f32_16x16x32_bf16((a), (b), (c), 0, 0, 0)

static __device__ __forceinline__ unsigned short f2bf(float f) {
  unsigned u = __float_as_uint(f);
  u += 0x7fffu + ((u >> 16) & 1u);  // RNE; inputs are finite
  return (unsigned short)(u >> 16);
}

// ---------------------------------------------------------------------------
// Weight transpose + fp32->bf16 convert: w[K][N] f32 -> wt[N][K] bf16
// ---------------------------------------------------------------------------
__global__ __launch_bounds__(256) void wt_transpose_kernel(
    const float* __restrict__ w, unsigned short* __restrict__ wt, int K, int N) {
  __shared__ float tile[32][33];
  const int n0 = blockIdx.x * 32, k0 = blockIdx.y * 32;
  const int tx = threadIdx.x & 31, ty = threadIdx.x >> 5;
#pragma unroll
  for (int i = 0; i < 4; ++i) {
    const int k = ty + i * 8;
    tile[k][tx] = w[(size_t)(k0 + k) * N + n0 + tx];
  }
  __syncthreads();
#pragma unroll
  for (int i = 0; i < 4; ++i) {
    const int n = ty + i * 8;
    wt[(size_t)(n0 + n) * K + k0 + tx] = f2bf(tile[tx][n]);
  }
}

// ---------------------------------------------------------------------------
// LayerNorm over C=512, fp32 in -> bf16 out. 1 wave per token, 4 tokens/block.
// ---------------------------------------------------------------------------
__global__ __launch_bounds__(256) void ln_bf16_kernel(
    const float* __restrict__ x, const float* __restrict__ gw,
    const float* __restrict__ bw, unsigned short* __restrict__ out) {
  const int wv = threadIdx.x >> 6, lane = threadIdx.x & 63;
  const size_t t = (size_t)blockIdx.x * 4 + wv;
  const float4* xr = (const float4*)(x + t * 512);
  const float4 v0 = xr[lane * 2];
  const float4 v1 = xr[lane * 2 + 1];
  float s = v0.x + v0.y + v0.z + v0.w + v1.x + v1.y + v1.z + v1.w;
  float ss = v0.x * v0.x + v0.y * v0.y + v0.z * v0.z + v0.w * v0.w +
             v1.x * v1.x + v1.y * v1.y + v1.z * v1.z + v1.w * v1.w;
#pragma unroll
  for (int m = 1; m < 64; m <<= 1) {
    s += __shfl_xor(s, m);
    ss += __shfl_xor(ss, m);
  }
  const float mean = s * (1.0f / 512.0f);
  const float var = fmaxf(ss * (1.0f / 512.0f) - mean * mean, 0.0f);
  const float rstd = rsqrtf(var + 1e-3f);
  const float4* gp = (const float4*)gw;
  const float4* bp = (const float4*)bw;
  const float4 g0 = gp[lane * 2], g1 = gp[lane * 2 + 1];
  const float4 b0 = bp[lane * 2], b1 = bp[lane * 2 + 1];
  uint4 o;
  o.x = (unsigned)f2bf((v0.x - mean) * rstd * g0.x + b0.x) |
        ((unsigned)f2bf((v0.y - mean) * rstd * g0.y + b0.y) << 16);
  o.y = (unsigned)f2bf((v0.z - mean) * rstd * g0.z + b0.z) |
        ((unsigned)f2bf((v0.w - mean) * rstd * g0.w + b0.w) << 16);
  o.z = (unsigned)f2bf((v1.x - mean) * rstd * g1.x + b1.x) |
        ((unsigned)f2bf((v1.y - mean) * rstd * g1.y + b1.y) << 16);
  o.w = (unsigned)f2bf((v1.z - mean) * rstd * g1.z + b1.z) |
        ((unsigned)f2bf((v1.w - mean) * rstd * g1.w + b1.w) << 16);
  *(uint4*)(out + t * 512 + lane * 8) = o;
}

// ---------------------------------------------------------------------------
// 256x256x64 8-phase bf16 GEMM (T2+T3+T4+T5): C = A[M][K] @ Bt[N][K]^T + bias
// 512 threads = 8 waves (2M x 4N), per-wave 128x64 out, BK=64, 2 LDS buffers.
// Quadrant-per-phase schedule (m201 order): P1 (0,0) reads A0+B0, P2 (0,1)
// reads B1, P3 (1,1) reads A1, P4 (1,0) register-only. Staging: P1/P2 ->
// next buffer bottom halves (tile g+1); P4 -> current buffer top halves
// (tile g+2, issued only after ALL current-buffer reads completed at P3's
// end barrier). vmcnt(4) once per K-tile, never drained to 0 in the loop.
// LDS swizzle: 16B chunk' = chunk ^ (row&7); linear LDS dest +
// inverse-swizzled global source (rule #21) + swizzled ds_read addresses.
// EPI: 0 = bf16 out, 1 = f32 out (+resid), 2 = bf16 gelu(out)
// Requires M%256==0, N%256==0, K%64==0, grid=(M/256)*(N/256) %8==0.
// ---------------------------------------------------------------------------
template <int EPI>
__global__ __launch_bounds__(512, 2) void gemm256_kernel(
    const unsigned short* __restrict__ A, const unsigned short* __restrict__ Bt,
    const float* __restrict__ bias, const float* __restrict__ resid,
    void* __restrict__ outv, int M, int N, int K) {
  __shared__ __align__(16) unsigned short lds[2][2][256 * 64];  // 128 KiB
  const int NT = K >> 6;
  const int nTn = N >> 8;
  const int bid = blockIdx.x, nwg = gridDim.x;
  const int swz = (bid & 7) * (nwg >> 3) + (bid >> 3);  // XCD-aware swizzle
  const int tmr = (swz / nTn) * 256, tnr = (swz % nTn) * 256;
  const int tid = threadIdx.x;
  const int l = tid & 63, w = tid >> 6;
  const int lr = l & 15, lg = l >> 4, x = lr & 7;
  const int wm = w >> 2, wn = w & 3;
  const int l8 = l >> 3;
  const int coff = ((l & 7) ^ l8) * 8;        // inverse-swizzled source chunk
  const int k0 = (lg ^ x) * 8, k1 = k0 ^ 32;  // swizzled read col offsets
  const int abase = (wm * 128 + lr) * 64;
  const int bbase = (wn * 64 + lr) * 64;

  f32x4 acc[8][4] = {};

#define STAGE_A(buf, row0, kt)                                                  \
  do {                                                                          \
    const int kte_ = (kt) < NT ? (kt) : (kt) - NT;                              \
    const unsigned short* s_ =                                                  \
        A + (size_t)(tmr + (row0) + w * 16 + l8) * K + kte_ * 64 + coff;        \
    GLDS16(s_, &lds[buf][0][((row0) + w * 16) * 64]);                           \
    GLDS16(s_ + (size_t)8 * K, &lds[buf][0][((row0) + w * 16 + 8) * 64]);       \
  } while (0)
#define STAGE_B(buf, row0, kt)                                                  \
  do {                                                                          \
    const int kte_ = (kt) < NT ? (kt) : (kt) - NT;                              \
    const unsigned short* s_ =                                                  \
        Bt + (size_t)(tnr + (row0) + w * 16 + l8) * K + kte_ * 64 + coff;       \
    GLDS16(s_, &lds[buf][1][((row0) + w * 16) * 64]);                           \
    GLDS16(s_ + (size_t)8 * K, &lds[buf][1][((row0) + w * 16 + 8) * 64]);       \
  } while (0)

  // Prologue: tile 0 complete (8 loads) + tile 1 top halves (4 loads).
  // vmcnt(4): tile 0 landed; the 4 tile-1 half-loads stay in flight.
  STAGE_A(0, 0, 0);
  STAGE_B(0, 0, 0);
  STAGE_A(0, 128, 0);
  STAGE_B(0, 128, 0);
  STAGE_A(1, 0, 1);
  STAGE_B(1, 0, 1);
  asm volatile("s_waitcnt vmcnt(4)" ::: "memory");
  BAR();
  SCHED0();

  for (int g = 0; g < NT; ++g) {
    const int cb = g & 1, nb = cb ^ 1;
    const unsigned short* sA = &lds[cb][0][0];
    const unsigned short* sB = &lds[cb][1][0];
    bf16x8 a0[4][2], a1[4][2], b0[2][2], b1[2][2];
    // ---- P1: read A0 (8) + B0 (4); stage NXT A-bot (tile g+1); MFMA (0,0)
#pragma unroll
    for (int m = 0; m < 4; ++m) {
      a0[m][0] = *(const bf16x8*)(sA + abase + m * 1024 + k0);
      a0[m][1] = *(const bf16x8*)(sA + abase + m * 1024 + k1);
    }
#pragma unroll
    for (int n = 0; n < 2; ++n) {
      b0[n][0] = *(const bf16x8*)(sB + bbase + n * 1024 + k0);
      b0[n][1] = *(const bf16x8*)(sB + bbase + n * 1024 + k1);
    }
    STAGE_A(nb, 128, g + 1);
    BAR();
    PRIO(1);
#pragma unroll
    for (int m = 0; m < 4; ++m)
#pragma unroll
      for (int n = 0; n < 2; ++n) {
        acc[m][n] = MFMA(a0[m][0], b0[n][0], acc[m][n]);
        acc[m][n] = MFMA(a0[m][1], b0[n][1], acc[m][n]);
      }
    PRIO(0);
    BAR();
    SCHED0();
    // ---- P2: read B1 (4); stage NXT B-bot (tile g+1); MFMA (0,1)
#pragma unroll
    for (int n = 0; n < 2; ++n) {
      b1[n][0] = *(const bf16x8*)(sB + bbase + 2048 + n * 1024 + k0);
      b1[n][1] = *(const bf16x8*)(sB + bbase + 2048 + n * 1024 + k1);
    }
    STAGE_B(nb, 128, g + 1);
    BAR();
    PRIO(1);
#pragma unroll
    for (int m = 0; m < 4; ++m)
#pragma unroll
      for (int n = 0; n < 2; ++n) {
        acc[m][2 + n] = MFMA(a0[m][0], b1[n][0], acc[m][2 + n]);
        acc[m][2 + n] = MFMA(a0[m][1], b1[n][1], acc[m][2 + n]);
      }
    PRIO(0);
    BAR();
    SCHED0();
    // ---- P3: read A1 (8); MFMA (1,1)  (no staging -> cb reads all complete
    //      by this phase's end barrier)
#pragma unroll
    for (int m = 0; m < 4; ++m) {
      a1[m][0] = *(const bf16x8*)(sA + abase + 4096 + m * 1024 + k0);
      a1[m][1] = *(const bf16x8*)(sA + abase + 4096 + m * 1024 + k1);
    }
    BAR();
    PRIO(1);
#pragma unroll
    for (int m = 0; m < 4; ++m)
#pragma unroll
      for (int n = 0; n < 2; ++n) {
        acc[4 + m][2 + n] = MFMA(a1[m][0], b1[n][0], acc[4 + m][2 + n]);
        acc[4 + m][2 + n] = MFMA(a1[m][1], b1[n][1], acc[4 + m][2 + n]);
      }
    PRIO(0);
    BAR();
    SCHED0();
    // ---- P4: stage CUR A-top + B-top (tile g+2); counted vmcnt; MFMA (1,0)
    STAGE_A(cb, 0, g + 2);
    STAGE_B(cb, 0, g + 2);
    asm volatile("s_waitcnt vmcnt(4)" ::: "memory");
    BAR();
    PRIO(1);
#pragma unroll
    for (int m = 0; m < 4; ++m)
#pragma unroll
      for (int n = 0; n < 2; ++n) {
        acc[4 + m][n] = MFMA(a1[m][0], b0[n][0], acc[4 + m][n]);
        acc[4 + m][n] = MFMA(a1[m][1], b0[n][1], acc[4 + m][n]);
      }
    PRIO(0);
    BAR();
    SCHED0();
  }
#undef STAGE_A
#undef STAGE_B

  // Epilogue (verified C/D mapping: col=lane&15, row=(lane>>4)*4+reg)
  const int row0 = tmr + wm * 128 + lg * 4;
  const int col0 = tnr + wn * 64 + lr;
#pragma unroll
  for (int n = 0; n < 4; ++n) {
    const int col = col0 + n * 16;
    const float bs = bias[col];
#pragma unroll
    for (int m = 0; m < 8; ++m) {
#pragma unroll
      for (int r = 0; r < 4; ++r) {
        const size_t idx = (size_t)(row0 + m * 16 + r) * N + col;
        float v = acc[m][n][r] + bs;
        if (EPI == 1) {
          ((float*)outv)[idx] = v + resid[idx];
        } else if (EPI == 2) {
          v = 0.5f * v * (1.0f + erff(v * 0.70710678118f));
          ((unsigned short*)outv)[idx] = f2bf(v);
        } else {
          ((unsigned short*)outv)[idx] = f2bf(v);
        }
      }
    }
  }
}

// ---------------------------------------------------------------------------
// Window attention: 1 wave per (window, head). WS=16, D=64, H=8.
// ---------------------------------------------------------------------------
__global__ __launch_bounds__(256) void attn_kernel(
    const unsigned short* __restrict__ qkv,
    const float* __restrict__ bias_table, unsigned short* __restrict__ out) {
  __shared__ __align__(16) unsigned short sVt[4][64 * 16];
  __shared__ __align__(16) unsigned short sP[4][16 * 16];
  const int wv = threadIdx.x >> 6, lane = threadIdx.x & 63;
  const int task = blockIdx.x * 4 + wv;
  const int w = task >> 3, h = task & 7;
  const int c = lane & 15, g = lane >> 4;
  const unsigned short* base =
      qkv + (size_t)w * 16 * 1536 + (size_t)c * 1536 + h * 64;
  const bf16x8 qf0 = *(const bf16x8*)(base + g * 8);
  const bf16x8 qf1 = *(const bf16x8*)(base + 32 + g * 8);
  const bf16x8 kf0 = *(const bf16x8*)(base + 512 + g * 8);
  const bf16x8 kf1 = *(const bf16x8*)(base + 512 + 32 + g * 8);
  const bf16x8 vf0 = *(const bf16x8*)(base + 1024 + g * 8);
  const bf16x8 vf1 = *(const bf16x8*)(base + 1024 + 32 + g * 8);
  unsigned short* vt = sVt[wv];
#pragma unroll
  for (int j = 0; j < 8; ++j) vt[(g * 8 + j) * 16 + c] = (unsigned short)vf0[j];
#pragma unroll
  for (int j = 0; j < 8; ++j) vt[(32 + g * 8 + j) * 16 + c] = (unsigned short)vf1[j];
  f32x4 s = {0.f, 0.f, 0.f, 0.f};
  s = MFMA(qf0, kf0, s);
  s = MFMA(qf1, kf1, s);
  float p[4];
#pragma unroll
  for (int r = 0; r < 4; ++r) {
    const int q = g * 4 + r;
    p[r] = s[r] * 0.125f + bias_table[(q - c + 15) * 8 + h];
  }
#pragma unroll
  for (int r = 0; r < 4; ++r) {
    float m = p[r];
    m = fmaxf(m, __shfl_xor(m, 1));
    m = fmaxf(m, __shfl_xor(m, 2));
    m = fmaxf(m, __shfl_xor(m, 4));
    m = fmaxf(m, __shfl_xor(m, 8));
    const float e = __expf(p[r] - m);
    float t = e;
    t += __shfl_xor(t, 1);
    t += __shfl_xor(t, 2);
    t += __shfl_xor(t, 4);
    t += __shfl_xor(t, 8);
    p[r] = e * __builtin_amdgcn_rcpf(t);
  }
  unsigned short* pb = sP[wv];
#pragma unroll
  for (int r = 0; r < 4; ++r) pb[(g * 4 + r) * 16 + c] = f2bf(p[r]);
  __syncthreads();
  bf16x8 pf;
#pragma unroll
  for (int j = 0; j < 8; ++j) pf[j] = 0;
  if (g < 2) pf = *(const bf16x8*)&pb[c * 16 + g * 8];
  const int kk0 = (g & 1) * 8;
  unsigned short* ob = out + (size_t)w * 16 * 512 + (size_t)c * 512 + h * 64;
#pragma unroll
  for (int ch = 0; ch < 4; ++ch) {
    const bf16x8 av = *(const bf16x8*)&vt[(ch * 16 + c) * 16 + kk0];
    f32x4 o = {0.f, 0.f, 0.f, 0.f};
    o = MFMA(av, pf, o);
    ushort4 pk;
    pk.x = f2bf(o[0]);
    pk.y = f2bf(o[1]);
    pk.z = f2bf(o[2]);
    pk.w = f2bf(o[3]);
    *(ushort4*)(ob + ch * 16 + g * 4) = pk;
  }
}

// ---------------------------------------------------------------------------
extern "C" void kernel_launch(void* const* d_in, const int* in_sizes, int n_in,
                              void* d_out, int out_size, void* d_ws,
                              size_t ws_size, hipStream_t stream) {
  (void)in_sizes; (void)n_in; (void)out_size;
  const float* x      = (const float*)d_in[0];
  const float* g1     = (const float*)d_in[1];
  const float* b1     = (const float*)d_in[2];
  const float* w_qkv  = (const float*)d_in[3];
  const float* b_qkv  = (const float*)d_in[4];
  const float* btab   = (const float*)d_in[5];
  const float* w_proj = (const float*)d_in[6];
  const float* b_proj = (const float*)d_in[7];
  const float* g2     = (const float*)d_in[8];
  const float* b2     = (const float*)d_in[9];
  const float* w_fc1  = (const float*)d_in[10];
  const float* b_fc1  = (const float*)d_in[11];
  const float* w_fc2  = (const float*)d_in[12];
  const float* b_fc2  = (const float*)d_in[13];
  float* out = (float*)d_out;

  char* ws = (char*)d_ws;
  const size_t OFF_BIG = 134217728ull;            // 128M
  const size_t OFF_ATT = OFF_BIG + 402653184ull;  // 128M + 384M
  const size_t OFF_WT  = OFF_BIG + 536870912ull;  // 128M + 512M
  if (ws_size < OFF_WT + 6291456ull) return;      // need ~646 MB
  unsigned short* hbuf   = (unsigned short*)(ws);
  unsigned short* qkvhid = (unsigned short*)(ws + OFF_BIG);
  unsigned short* attnb  = (unsigned short*)(ws + OFF_ATT);
  unsigned short* wqkvT  = (unsigned short*)(ws + OFF_WT);
  unsigned short* wprojT = wqkvT + 512 * 1536;
  unsigned short* wfc1T  = wprojT + 512 * 512;
  unsigned short* wfc2T  = wfc1T + 512 * 2048;

  wt_transpose_kernel<<<dim3(1536 / 32, 512 / 32), 256, 0, stream>>>(w_qkv, wqkvT, 512, 1536);
  wt_transpose_kernel<<<dim3(512 / 32, 512 / 32), 256, 0, stream>>>(w_proj, wprojT, 512, 512);
  wt_transpose_kernel<<<dim3(2048 / 32, 512 / 32), 256, 0, stream>>>(w_fc1, wfc1T, 512, 2048);
  wt_transpose_kernel<<<dim3(512 / 32, 2048 / 32), 256, 0, stream>>>(w_fc2, wfc2T, 2048, 512);

  // 1) h = LN1(x)  (bf16)
  ln_bf16_kernel<<<32768, 256, 0, stream>>>(x, g1, b1, hbuf);
  // 2) qkv = h @ w_qkv + b_qkv  (bf16)
  gemm256_kernel<0><<<3072, 512, 0, stream>>>(hbuf, wqkvT, b_qkv, nullptr,
                                              qkvhid, 131072, 1536, 512);
  // 3) window attention -> attn_out (bf16)
  attn_kernel<<<16384, 256, 0, stream>>>(qkvhid, btab, attnb);
  // 4) x1 = attn_out @ w_proj + b_proj + x  (f32, into d_out)
  gemm256_kernel<1><<<1024, 512, 0, stream>>>(attnb, wprojT, b_proj, x, out,
                                              131072, 512, 512);
  // 5) h2 = LN2(x1)  (bf16)
  ln_bf16_kernel<<<32768, 256, 0, stream>>>(out, g2, b2, hbuf);
  // 6) hid = gelu(h2 @ w_fc1 + b_fc1)  (bf16)
  gemm256_kernel<2><<<4096, 512, 0, stream>>>(hbuf, wfc1T, b_fc1, nullptr,
                                              qkvhid, 131072, 2048, 512);
  // 7) out = hid @ w_fc2 + b_fc2 + x1  (f32, in-place on d_out)
  gemm256_kernel<1><<<1024, 512, 0, stream>>>(qkvhid, wfc2T, b_fc2, out, out,
                                              131072, 512, 2048);
}